// Round 1
// baseline (178.115 us; speedup 1.0000x reference)
//
#include <hip/hip_runtime.h>
#include <hip/hip_bf16.h>
#include <stdint.h>

// ---------------------------------------------------------------------------
// SupervisedContrastiveLoss, B=4096, D=1024, C=32, T=0.1, eps=1e-8
// out = (1/B) * sum_i [ log(denom_i)*W_i - S_i ]
//   denom_i = sum_{j!=i} exp(Z_ij)            (needs full Z -> fused MFMA GEMM)
//   W_i     = (classCount[l_i]-1) + pw*(sl_i . colsum(SL))
//   S_i     = sum_j Z_ij*pos_ij + pw*10*(sl_i . rnG_i),  rnG = rn@(rn^T@SL)
// Z symmetric -> only upper-triangular 128x128 tiles (528 blocks), row+col sums.
// ---------------------------------------------------------------------------

typedef float f32x4 __attribute__((ext_vector_type(4)));
typedef __bf16 bf16x8 __attribute__((ext_vector_type(8)));
typedef unsigned short u16x8 __attribute__((ext_vector_type(8)));

#define INV_T 10.0f

// workspace layout (bytes)
#define OFF_RNBF  0                         // 4096*1024*2 = 8388608
#define OFF_DENOM 8388608                   // 4096*4
#define OFF_POSS  (OFF_DENOM + 16384)
#define OFF_G     (OFF_POSS + 16384)        // 1024*32*4 = 131072
#define OFF_CSUM  (OFF_G + 131072)         // 32*4 (+pad)
#define OFF_CCNT  (OFF_CSUM + 128)
#define OFF_OACC  (OFF_CCNT + 128)          // double
#define OFF_RNG   (OFF_OACC + 16)           // 4096*32*4 = 524288
#define WS_END    (OFF_RNG + 524288)
#define ZERO_BYTES (WS_END - OFF_DENOM)

// ---------------- normalize rows -> bf16 ----------------
__global__ __launch_bounds__(256) void scl_normalize(const float* __restrict__ rep,
                                                     uint16_t* __restrict__ rnbf) {
    int row = blockIdx.x;
    int t = threadIdx.x;
    const float4* src = reinterpret_cast<const float4*>(rep + (size_t)row * 1024);
    float4 v = src[t];
    float s = v.x * v.x + v.y * v.y + v.z * v.z + v.w * v.w;
#pragma unroll
    for (int m = 1; m < 64; m <<= 1) s += __shfl_xor(s, m, 64);
    __shared__ float red[4];
    if ((t & 63) == 0) red[t >> 6] = s;
    __syncthreads();
    s = red[0] + red[1] + red[2] + red[3];
    float nf = 1.0f / fmaxf(sqrtf(s), 1e-8f);
    ushort4 o;
    o.x = __builtin_bit_cast(unsigned short, (__bf16)(v.x * nf));
    o.y = __builtin_bit_cast(unsigned short, (__bf16)(v.y * nf));
    o.z = __builtin_bit_cast(unsigned short, (__bf16)(v.z * nf));
    o.w = __builtin_bit_cast(unsigned short, (__bf16)(v.w * nf));
    reinterpret_cast<ushort4*>(rnbf + (size_t)row * 1024)[t] = o;
}

// ---------------- colsum of soft_labels + class histogram ----------------
__global__ __launch_bounds__(256) void scl_prep(const float* __restrict__ sl,
                                                const int* __restrict__ labels,
                                                float* __restrict__ csum,
                                                int* __restrict__ ccnt) {
    __shared__ float part[8][32];
    __shared__ int bins[32];
    int t = threadIdx.x, b = blockIdx.x;
    if (t < 32) bins[t] = 0;
    __syncthreads();
    if (t < 128) atomicAdd(&bins[labels[b * 128 + t]], 1);
    int c = t & 31, rg = t >> 5;
    float s = 0.f;
#pragma unroll 4
    for (int k = 0; k < 16; ++k) {
        int i = b * 128 + rg * 16 + k;
        s += sl[i * 32 + c];
    }
    part[rg][c] = s;
    __syncthreads();
    if (t < 32) {
        float tot = 0.f;
#pragma unroll
        for (int g = 0; g < 8; ++g) tot += part[g][t];
        atomicAdd(&csum[t], tot);
        atomicAdd(&ccnt[t], bins[t]);
    }
}

// ---------------- G = rn^T @ SL  [1024 x 32], split-K with atomics ----------------
__global__ __launch_bounds__(256) void scl_G(const uint16_t* __restrict__ rnbf,
                                             const float* __restrict__ sl,
                                             float* __restrict__ G) {
    int t = threadIdx.x;
    int dblk = blockIdx.x & 31, ks = blockIdx.x >> 5;  // 32 d-blocks x 16 k-splits
    int dl = t >> 3, cq = t & 7;
    int d = dblk * 32 + dl;
    const f32x4* sl4 = (const f32x4*)sl;
    f32x4 acc = {0.f, 0.f, 0.f, 0.f};
    int i0 = ks * 256;
#pragma unroll 4
    for (int k = 0; k < 256; ++k) {
        int i = i0 + k;
        float v = (float)__builtin_bit_cast(__bf16, rnbf[(size_t)i * 1024 + d]);
        f32x4 w = sl4[i * 8 + cq];
        acc += w * v;
    }
    float* gp = &G[d * 32 + cq * 4];
    atomicAdd(gp + 0, acc[0]);
    atomicAdd(gp + 1, acc[1]);
    atomicAdd(gp + 2, acc[2]);
    atomicAdd(gp + 3, acc[3]);
}

// ---------------- rnG = rn @ G  [4096 x 32], split-D with atomics ----------------
__global__ __launch_bounds__(256) void scl_rnG(const uint16_t* __restrict__ rnbf,
                                               const float* __restrict__ G,
                                               float* __restrict__ rnG) {
    int t = threadIdx.x;
    int dh = t >> 7;          // 0..1 (d-halves)
    int r = (t >> 3) & 15;    // row within block
    int cq = t & 7;
    int row = blockIdx.x * 16 + r;
    const f32x4* G4 = (const f32x4*)G;
    const u16x8* rn8 = (const u16x8*)(rnbf + (size_t)row * 1024);
    f32x4 acc = {0.f, 0.f, 0.f, 0.f};
    int d80 = dh * 64;
#pragma unroll 2
    for (int d8 = 0; d8 < 64; ++d8) {
        u16x8 rv = rn8[d80 + d8];
#pragma unroll
        for (int j = 0; j < 8; ++j) {
            float v = (float)__builtin_bit_cast(__bf16, (unsigned short)rv[j]);
            acc += G4[((d80 + d8) * 8 + j) * 8 + cq] * v;
        }
    }
    float* op = &rnG[row * 32 + cq * 4];
    atomicAdd(op + 0, acc[0]);
    atomicAdd(op + 1, acc[1]);
    atomicAdd(op + 2, acc[2]);
    atomicAdd(op + 3, acc[3]);
}

// ---------------- main fused GEMM: rowsum/colsum of exp(Z) and pos*Z ----------------
__global__ __launch_bounds__(256) void scl_gemm(const uint16_t* __restrict__ rnbf,
                                                const int* __restrict__ labels,
                                                float* __restrict__ denom,
                                                float* __restrict__ posS) {
    __shared__ __align__(16) uint16_t As[128 * 64];
    __shared__ __align__(16) uint16_t Bs[128 * 64];
    __shared__ int lblA[128], lblB[128];

    // upper-triangular tile decode: block L -> (bi <= bj)
    int L = blockIdx.x;
    int bi = 0, rem = L;
    while (rem >= 32 - bi) { rem -= 32 - bi; ++bi; }
    int bj = bi + rem;
    int rowA0 = bi * 128, colB0 = bj * 128;

    int tid = threadIdx.x;
    if (tid < 128) {
        lblA[tid] = labels[rowA0 + tid];
        lblB[tid] = labels[colB0 + tid];
    }

    // staging: thread t owns chunks (t + 256*m); row = t>>3 + 32m, chunk col c8 = t&7
    int c8 = tid & 7, r0 = tid >> 3;
    const f32x4* gA = (const f32x4*)(rnbf + (size_t)(rowA0 + r0) * 1024 + c8 * 8);
    const f32x4* gB = (const f32x4*)(rnbf + (size_t)(colB0 + r0) * 1024 + c8 * 8);
    int ldsSt = r0 * 64 + ((c8 ^ (r0 & 7)) * 8);  // XOR swizzle, elements

    int lane = tid & 63, warp = tid >> 6;
    int wr = warp >> 1, wc = warp & 1;
    int m_ = lane & 15, g = lane >> 4;

    f32x4 acc[4][4];
#pragma unroll
    for (int a = 0; a < 4; ++a)
#pragma unroll
        for (int b = 0; b < 4; ++b) acc[a][b] = (f32x4){0.f, 0.f, 0.f, 0.f};

    f32x4 pfA[4], pfB[4];
#pragma unroll
    for (int m = 0; m < 4; ++m) { pfA[m] = gA[m * 4096]; pfB[m] = gB[m * 4096]; }

    for (int kt = 0; kt < 16; ++kt) {
        __syncthreads();
#pragma unroll
        for (int m = 0; m < 4; ++m) {
            *(f32x4*)&As[ldsSt + m * 2048] = pfA[m];
            *(f32x4*)&Bs[ldsSt + m * 2048] = pfB[m];
        }
        __syncthreads();
        if (kt < 15) {
            int ko = (kt + 1) * 8;
#pragma unroll
            for (int m = 0; m < 4; ++m) { pfA[m] = gA[m * 4096 + ko]; pfB[m] = gB[m * 4096 + ko]; }
        }
#pragma unroll
        for (int s = 0; s < 2; ++s) {
            bf16x8 af[4], bf[4];
#pragma unroll
            for (int ti = 0; ti < 4; ++ti) {
                int rowLoc = wr * 64 + ti * 16 + m_;
                int off = rowLoc * 64 + (((s * 4 + g) ^ (m_ & 7)) * 8);
                af[ti] = __builtin_bit_cast(bf16x8, *(const f32x4*)&As[off]);
            }
#pragma unroll
            for (int tj = 0; tj < 4; ++tj) {
                int colLoc = wc * 64 + tj * 16 + m_;
                int off = colLoc * 64 + (((s * 4 + g) ^ (m_ & 7)) * 8);
                bf[tj] = __builtin_bit_cast(bf16x8, *(const f32x4*)&Bs[off]);
            }
#pragma unroll
            for (int ti = 0; ti < 4; ++ti)
#pragma unroll
                for (int tj = 0; tj < 4; ++tj)
                    acc[ti][tj] = __builtin_amdgcn_mfma_f32_16x16x32_bf16(
                        af[ti], bf[tj], acc[ti][tj], 0, 0, 0);
        }
    }

    // epilogue: C layout col=lane&15, row=(lane>>4)*4+reg
    bool isDiag = (bi == bj);
    int cl = m_;
    float colE[4] = {0.f, 0.f, 0.f, 0.f}, colP[4] = {0.f, 0.f, 0.f, 0.f};
#pragma unroll
    for (int ti = 0; ti < 4; ++ti) {
        int rowLoc = wr * 64 + ti * 16 + g * 4;
        float rE[4] = {0.f, 0.f, 0.f, 0.f}, rP[4] = {0.f, 0.f, 0.f, 0.f};
        int lr[4];
#pragma unroll
        for (int r = 0; r < 4; ++r) lr[r] = lblA[rowLoc + r];
#pragma unroll
        for (int tj = 0; tj < 4; ++tj) {
            int colLoc = wc * 64 + tj * 16 + cl;
            int gCol = colB0 + colLoc;
            int lc = lblB[colLoc];
            f32x4 a = acc[ti][tj];
#pragma unroll
            for (int r = 0; r < 4; ++r) {
                int gRow = rowA0 + rowLoc + r;
                float z = INV_T * a[r];
                float e = __expf(z);
                bool offd = (gRow != gCol);
                if (!offd) e = 0.f;
                rE[r] += e;
                colE[tj] += e;
                if (offd && (lr[r] == lc)) { rP[r] += z; colP[tj] += z; }
            }
        }
#pragma unroll
        for (int r = 0; r < 4; ++r) {
            float v = rE[r], p = rP[r];
#pragma unroll
            for (int msk = 1; msk < 16; msk <<= 1) {
                v += __shfl_xor(v, msk, 64);
                p += __shfl_xor(p, msk, 64);
            }
            if (cl == 0) {
                int gRow = rowA0 + rowLoc + r;
                atomicAdd(&denom[gRow], v);
                atomicAdd(&posS[gRow], p);
            }
        }
    }
    if (!isDiag) {
#pragma unroll
        for (int tj = 0; tj < 4; ++tj) {
            float v = colE[tj], p = colP[tj];
            v += __shfl_xor(v, 16, 64); p += __shfl_xor(p, 16, 64);
            v += __shfl_xor(v, 32, 64); p += __shfl_xor(p, 32, 64);
            if (g == 0) {
                int gCol = colB0 + wc * 64 + tj * 16 + cl;
                atomicAdd(&denom[gCol], v);
                atomicAdd(&posS[gCol], p);
            }
        }
    }
}

// ---------------- finalize: per-row term, double accumulation ----------------
__global__ __launch_bounds__(256) void scl_finalize(const float* __restrict__ denom,
                                                    const float* __restrict__ posS,
                                                    const float* __restrict__ sl,
                                                    const int* __restrict__ labels,
                                                    const int* __restrict__ ccnt,
                                                    const float* __restrict__ csum,
                                                    const float* __restrict__ rnG,
                                                    const int* __restrict__ pwp,
                                                    double* __restrict__ oacc) {
    int i = blockIdx.x * 256 + threadIdx.x;
    int bits = *pwp;
    float pw = (bits >= -(1 << 22) && bits <= (1 << 22)) ? (float)bits : __int_as_float(bits);
    const f32x4* sl4 = (const f32x4*)sl;
    const f32x4* rg4 = (const f32x4*)rnG;
    const f32x4* cs4 = (const f32x4*)csum;
    float dW = 0.f, dS = 0.f;
#pragma unroll
    for (int q = 0; q < 8; ++q) {
        f32x4 s = sl4[i * 8 + q];
        f32x4 c = cs4[q];
        f32x4 r = rg4[i * 8 + q];
        dW += s[0] * c[0] + s[1] * c[1] + s[2] * c[2] + s[3] * c[3];
        dS += s[0] * r[0] + s[1] * r[1] + s[2] * r[2] + s[3] * r[3];
    }
    float W = (float)(ccnt[labels[i]] - 1) + pw * dW;
    float S = posS[i] + pw * INV_T * dS;
    float term = __logf(denom[i]) * W - S;
    double td = (double)term;
#pragma unroll
    for (int m = 1; m < 64; m <<= 1) td += __shfl_xor(td, m, 64);
    __shared__ double wsum[4];
    if ((threadIdx.x & 63) == 0) wsum[threadIdx.x >> 6] = td;
    __syncthreads();
    if (threadIdx.x == 0) atomicAdd(oacc, wsum[0] + wsum[1] + wsum[2] + wsum[3]);
}

__global__ void scl_final(const double* __restrict__ oacc, float* __restrict__ out) {
    out[0] = (float)(oacc[0] * (1.0 / 4096.0));
}

// ---------------------------------------------------------------------------
extern "C" void kernel_launch(void* const* d_in, const int* in_sizes, int n_in,
                              void* d_out, int out_size, void* d_ws, size_t ws_size,
                              hipStream_t stream) {
    const float* rep = (const float*)d_in[0];
    const float* sl = (const float*)d_in[1];
    const int* labels = (const int*)d_in[2];
    const int* pwp = (const int*)d_in[3];

    char* ws = (char*)d_ws;
    uint16_t* rnbf = (uint16_t*)(ws + OFF_RNBF);
    float* denom = (float*)(ws + OFF_DENOM);
    float* posS = (float*)(ws + OFF_POSS);
    float* G = (float*)(ws + OFF_G);
    float* csum = (float*)(ws + OFF_CSUM);
    int* ccnt = (int*)(ws + OFF_CCNT);
    double* oacc = (double*)(ws + OFF_OACC);
    float* rnG = (float*)(ws + OFF_RNG);

    hipMemsetAsync(ws + OFF_DENOM, 0, ZERO_BYTES, stream);

    scl_normalize<<<4096, 256, 0, stream>>>(rep, rnbf);
    scl_prep<<<32, 256, 0, stream>>>(sl, labels, csum, ccnt);
    scl_G<<<512, 256, 0, stream>>>(rnbf, sl, G);
    scl_rnG<<<256, 256, 0, stream>>>(rnbf, G, rnG);
    scl_gemm<<<528, 256, 0, stream>>>(rnbf, labels, denom, posS);
    scl_finalize<<<16, 256, 0, stream>>>(denom, posS, sl, labels, ccnt, csum, rnG, pwp, oacc);
    scl_final<<<1, 1, 0, stream>>>(oacc, (float*)d_out);
}